// Round 3
// baseline (2065.792 us; speedup 1.0000x reference)
//
#include <hip/hip_runtime.h>
#include <cstdint>
#include <cstddef>

#define NN 50000
#define NE 800000
#define NG 256
#define NLAY 7
#define NBLK 782   // gemm blocks (64 rows each)

__device__ __forceinline__ float4 ld4(const float* p) { return *(const float4*)p; }
__device__ __forceinline__ void acc4(float4& a, const float4 b) {
  a.x += b.x; a.y += b.y; a.z += b.z; a.w += b.w;
}

// ---------------- init: zero counts + pooled ----------------
__global__ void k_zero(int* __restrict__ counts, float* __restrict__ pooled) {
  int i = blockIdx.x * 256 + threadIdx.x;  // grid 1792 -> 458752
  if (i < NN) counts[i] = 0;
  if (i < NG * 1792) pooled[i] = 0.f;
}

__global__ void k_hist(const int* __restrict__ edge, int* __restrict__ counts) {
  int e = blockIdx.x * 256 + threadIdx.x;
  if (e < NE) atomicAdd(&counts[edge[NE + e]], 1);
}

// ---------------- parallel CSR scan ----------------
__global__ void k_part(const int* __restrict__ counts, int* __restrict__ bsum) {
  __shared__ int sm[256];
  int b = blockIdx.x, t = threadIdx.x;
  int i = b * 256 + t;
  sm[t] = (i < NN) ? counts[i] : 0;
  __syncthreads();
  for (int s = 128; s > 0; s >>= 1) {
    if (t < s) sm[t] += sm[t + s];
    __syncthreads();
  }
  if (t == 0) bsum[b] = sm[0];
}

__global__ void k_bscan(const int* __restrict__ bsum, int* __restrict__ boff,
                        int* __restrict__ row_ptr) {
  __shared__ int sm[256];
  int t = threadIdx.x;
  int v = (t < 196) ? bsum[t] : 0;
  sm[t] = v;
  __syncthreads();
  int val = v;
  for (int off = 1; off < 256; off <<= 1) {
    int o = (t >= off) ? sm[t - off] : 0;
    __syncthreads();
    val += o;
    sm[t] = val;
    __syncthreads();
  }
  if (t < 196) boff[t] = val - v;  // exclusive
  if (t == 255) row_ptr[NN] = val; // total = NE
}

__global__ void k_rowptr(const int* __restrict__ counts, const int* __restrict__ boff,
                         int* __restrict__ row_ptr, int* __restrict__ cursor) {
  __shared__ int sm[256];
  int b = blockIdx.x, t = threadIdx.x;
  int i = b * 256 + t;
  int c = (i < NN) ? counts[i] : 0;
  sm[t] = c;
  __syncthreads();
  int val = c;
  for (int off = 1; off < 256; off <<= 1) {
    int o = (t >= off) ? sm[t - off] : 0;
    __syncthreads();
    val += o;
    sm[t] = val;
    __syncthreads();
  }
  int ex = val - c + boff[b];
  if (i < NN) { row_ptr[i] = ex; cursor[i] = ex; }
}

__global__ void k_fill(const int* __restrict__ edge, int* __restrict__ cursor,
                       int* __restrict__ csr_src) {
  int e = blockIdx.x * 256 + threadIdx.x;
  if (e < NE) {
    int pos = atomicAdd(&cursor[edge[NE + e]], 1);
    csr_src[pos] = edge[e];
  }
}

// ---------------- Aggregation: out[r] = h[r] + sum_{s in CSR[r]} h[s] ----------------
__global__ __launch_bounds__(256) void k_agg(
    const float* __restrict__ h, const int* __restrict__ row_ptr,
    const int* __restrict__ csr_src, float* __restrict__ out)
{
  int tid = threadIdx.x;
  int r = blockIdx.x * 32 + (tid >> 3);
  int sub = tid & 7;
  if (r >= NN) return;
  const float* hp = h + ((size_t)r << 7) + (sub << 4);
  float4 a0 = ld4(hp), a1 = ld4(hp + 4), a2 = ld4(hp + 8), a3 = ld4(hp + 12);
  float4 b0 = make_float4(0,0,0,0), b1 = b0, b2 = b0, b3 = b0;
  int e = row_ptr[r], e1 = row_ptr[r + 1];
  for (; e + 1 < e1; e += 2) {
    const float* p0 = h + ((size_t)csr_src[e] << 7) + (sub << 4);
    const float* p1 = h + ((size_t)csr_src[e + 1] << 7) + (sub << 4);
    float4 v0 = ld4(p0), v1 = ld4(p0 + 4), v2 = ld4(p0 + 8), v3 = ld4(p0 + 12);
    float4 w0 = ld4(p1), w1 = ld4(p1 + 4), w2 = ld4(p1 + 8), w3 = ld4(p1 + 12);
    acc4(a0, v0); acc4(a1, v1); acc4(a2, v2); acc4(a3, v3);
    acc4(b0, w0); acc4(b1, w1); acc4(b2, w2); acc4(b3, w3);
  }
  if (e < e1) {
    const float* p0 = h + ((size_t)csr_src[e] << 7) + (sub << 4);
    acc4(a0, ld4(p0)); acc4(a1, ld4(p0 + 4)); acc4(a2, ld4(p0 + 8)); acc4(a3, ld4(p0 + 12));
  }
  acc4(a0, b0); acc4(a1, b1); acc4(a2, b2); acc4(a3, b3);
  float* op = out + ((size_t)r << 7) + (sub << 4);
  *(float4*)op = a0; *(float4*)(op + 4) = a1;
  *(float4*)(op + 8) = a2; *(float4*)(op + 12) = a3;
}

// ---------------- GEMM1: z1 = agg @ W1 + b1, fused per-block BN partial stats ----------------
__global__ __launch_bounds__(256) void k_gemm_bn(
    const float* __restrict__ in, const float* __restrict__ W,
    const float* __restrict__ bias, float* __restrict__ out,
    float* __restrict__ psum, float* __restrict__ psq)
{
  __shared__ float zs[64][132];
  __shared__ float wsm[32][128];
  const int tid = threadIdx.x;
  const int m0 = blockIdx.x * 64;
  const int lane = tid & 31;
  const int rgrp = tid >> 5;
  for (int pass = 0; pass < 8; ++pass) {
    const int lr = pass * 8 + rgrp;
    const int r = m0 + lr;
    float4 v = make_float4(0.f, 0.f, 0.f, 0.f);
    if (r < NN) v = ld4(in + ((size_t)r << 7) + (lane << 2));
    *(float4*)&zs[lr][lane << 2] = v;
  }

  float acc[8][4];
  #pragma unroll
  for (int i = 0; i < 8; ++i) { acc[i][0]=0.f; acc[i][1]=0.f; acc[i][2]=0.f; acc[i][3]=0.f; }
  const int tm = tid >> 5, tn = tid & 31;
  for (int k0 = 0; k0 < 128; k0 += 32) {
    __syncthreads();
    #pragma unroll
    for (int j = 0; j < 16; ++j) {
      int idx = tid + j * 256;
      wsm[idx >> 7][idx & 127] = W[((size_t)(k0 + (idx >> 7)) << 7) + (idx & 127)];
    }
    __syncthreads();
    #pragma unroll 4
    for (int k = 0; k < 32; ++k) {
      float4 bv = *(const float4*)&wsm[k][tn << 2];
      #pragma unroll
      for (int i = 0; i < 8; ++i) {
        float av = zs[(tm << 3) + i][k0 + k];
        acc[i][0] = fmaf(av, bv.x, acc[i][0]);
        acc[i][1] = fmaf(av, bv.y, acc[i][1]);
        acc[i][2] = fmaf(av, bv.z, acc[i][2]);
        acc[i][3] = fmaf(av, bv.w, acc[i][3]);
      }
    }
  }
  float4 bb = ld4(bias + (tn << 2));
  float s0=0,s1=0,s2=0,s3=0,q0=0,q1=0,q2=0,q3=0;
  #pragma unroll
  for (int i = 0; i < 8; ++i) {
    int r = m0 + (tm << 3) + i;
    if (r < NN) {
      float4 o = make_float4(acc[i][0] + bb.x, acc[i][1] + bb.y,
                             acc[i][2] + bb.z, acc[i][3] + bb.w);
      *(float4*)(out + ((size_t)r << 7) + (tn << 2)) = o;
      s0 += o.x; q0 += o.x*o.x;
      s1 += o.y; q1 += o.y*o.y;
      s2 += o.z; q2 += o.z*o.z;
      s3 += o.w; q3 += o.w*o.w;
    }
  }
  // reduce over tm (8 groups) per column
  __syncthreads();
  float* reds = (float*)zs;          // 1024 floats
  float* redq = ((float*)zs) + 1024; // 1024 floats
  int cb = tn << 2;
  reds[(cb+0)*8+tm]=s0; reds[(cb+1)*8+tm]=s1; reds[(cb+2)*8+tm]=s2; reds[(cb+3)*8+tm]=s3;
  redq[(cb+0)*8+tm]=q0; redq[(cb+1)*8+tm]=q1; redq[(cb+2)*8+tm]=q2; redq[(cb+3)*8+tm]=q3;
  __syncthreads();
  if (tid < 128) {
    float s = 0.f, q = 0.f;
    #pragma unroll
    for (int k = 0; k < 8; ++k) { s += reds[tid*8+k]; q += redq[tid*8+k]; }
    psum[blockIdx.x * 128 + tid] = s;
    psq[blockIdx.x * 128 + tid] = q;
  }
}

// ---------------- BN finalize: ab[0:128]=scale, ab[128:256]=shift ----------------
__global__ void k_bnstat2(const float* __restrict__ psum, const float* __restrict__ psq,
                          const float* __restrict__ gamma, const float* __restrict__ beta,
                          float* __restrict__ ab) {
  __shared__ float shs[256], shq[256];
  int t = threadIdx.x;           // 256
  int col = t & 127, half = t >> 7;
  float s = 0.f, q = 0.f;
  for (int b = half; b < NBLK; b += 2) {
    s += psum[b * 128 + col];
    q += psq[b * 128 + col];
  }
  shs[t] = s; shq[t] = q;
  __syncthreads();
  if (t < 128) {
    s += shs[t + 128]; q += shq[t + 128];
    float mean = s * (1.f / NN);
    float var = q * (1.f / NN) - mean * mean;
    float rstd = rsqrtf(var + 1e-5f);
    float a = gamma[col] * rstd;
    ab[col] = a;
    ab[128 + col] = beta[col] - mean * a;
  }
}

// ---------------- GEMM2: h = relu(affrelu(z1) @ W2 + b2), fused pooling ----------------
__global__ __launch_bounds__(256) void k_gemm_pool(
    const float* __restrict__ in, const float* __restrict__ ab,
    const float* __restrict__ W, const float* __restrict__ bias,
    float* __restrict__ out, const int* __restrict__ batch,
    float* __restrict__ pooled, int layer)
{
  __shared__ float zs[64][132];
  __shared__ float wsm[32][128];
  const int tid = threadIdx.x;
  const int m0 = blockIdx.x * 64;
  const int lane = tid & 31;
  const int rgrp = tid >> 5;
  float4 aa = ld4(ab + (lane << 2));
  float4 ob = ld4(ab + 128 + (lane << 2));
  for (int pass = 0; pass < 8; ++pass) {
    const int lr = pass * 8 + rgrp;
    const int r = m0 + lr;
    float4 v = make_float4(0.f, 0.f, 0.f, 0.f);
    if (r < NN) v = ld4(in + ((size_t)r << 7) + (lane << 2));
    float4 y;
    y.x = fmaxf(fmaf(aa.x, v.x, ob.x), 0.f);
    y.y = fmaxf(fmaf(aa.y, v.y, ob.y), 0.f);
    y.z = fmaxf(fmaf(aa.z, v.z, ob.z), 0.f);
    y.w = fmaxf(fmaf(aa.w, v.w, ob.w), 0.f);
    *(float4*)&zs[lr][lane << 2] = y;
  }

  float acc[8][4];
  #pragma unroll
  for (int i = 0; i < 8; ++i) { acc[i][0]=0.f; acc[i][1]=0.f; acc[i][2]=0.f; acc[i][3]=0.f; }
  const int tm = tid >> 5, tn = tid & 31;
  for (int k0 = 0; k0 < 128; k0 += 32) {
    __syncthreads();
    #pragma unroll
    for (int j = 0; j < 16; ++j) {
      int idx = tid + j * 256;
      wsm[idx >> 7][idx & 127] = W[((size_t)(k0 + (idx >> 7)) << 7) + (idx & 127)];
    }
    __syncthreads();
    #pragma unroll 4
    for (int k = 0; k < 32; ++k) {
      float4 bv = *(const float4*)&wsm[k][tn << 2];
      #pragma unroll
      for (int i = 0; i < 8; ++i) {
        float av = zs[(tm << 3) + i][k0 + k];
        acc[i][0] = fmaf(av, bv.x, acc[i][0]);
        acc[i][1] = fmaf(av, bv.y, acc[i][1]);
        acc[i][2] = fmaf(av, bv.z, acc[i][2]);
        acc[i][3] = fmaf(av, bv.w, acc[i][3]);
      }
    }
  }
  float4 bb = ld4(bias + (tn << 2));
  // apply relu into acc, store
  int bgi[8];
  #pragma unroll
  for (int i = 0; i < 8; ++i) {
    int r = m0 + (tm << 3) + i;
    bgi[i] = (r < NN) ? batch[r] : -1;
    if (r < NN) {
      acc[i][0] = fmaxf(acc[i][0] + bb.x, 0.f);
      acc[i][1] = fmaxf(acc[i][1] + bb.y, 0.f);
      acc[i][2] = fmaxf(acc[i][2] + bb.z, 0.f);
      acc[i][3] = fmaxf(acc[i][3] + bb.w, 0.f);
      *(float4*)(out + ((size_t)r << 7) + (tn << 2)) =
          make_float4(acc[i][0], acc[i][1], acc[i][2], acc[i][3]);
    }
  }
  // fused pooling: rows m0..m0+63 span batch[m0]..batch[min(m0+63,NN-1)] graphs
  int gstart = batch[m0];
  int gend = batch[(m0 + 63 < NN) ? (m0 + 63) : (NN - 1)];
  float* reds = (float*)zs;
  float* redm = ((float*)zs) + 1024;
  int cb = tn << 2;
  for (int g = gstart; g <= gend; ++g) {
    float s[4] = {0.f,0.f,0.f,0.f}, mx[4] = {0.f,0.f,0.f,0.f};
    #pragma unroll
    for (int i = 0; i < 8; ++i) {
      if (bgi[i] == g) {
        s[0] += acc[i][0]; mx[0] = fmaxf(mx[0], acc[i][0]);
        s[1] += acc[i][1]; mx[1] = fmaxf(mx[1], acc[i][1]);
        s[2] += acc[i][2]; mx[2] = fmaxf(mx[2], acc[i][2]);
        s[3] += acc[i][3]; mx[3] = fmaxf(mx[3], acc[i][3]);
      }
    }
    __syncthreads();
    #pragma unroll
    for (int j = 0; j < 4; ++j) {
      reds[(cb+j)*8+tm] = s[j];
      redm[(cb+j)*8+tm] = mx[j];
    }
    __syncthreads();
    if (tid < 128) {
      float ss = 0.f, sm = 0.f;
      #pragma unroll
      for (int k = 0; k < 8; ++k) { ss += reds[tid*8+k]; sm = fmaxf(sm, redm[tid*8+k]); }
      if (ss != 0.f) atomicAdd(&pooled[g * 1792 + layer * 128 + tid], ss);
      if (sm != 0.f)
        atomicMax((int*)&pooled[g * 1792 + 896 + layer * 128 + tid], __float_as_int(sm));
    }
  }
}

// ---------------- Final MLP: split-K partials ----------------
__global__ __launch_bounds__(256) void k_mlp1a(
    const float* __restrict__ P, const float* __restrict__ Wl1,
    float* __restrict__ part)
{
  __shared__ float pt[64][33];
  __shared__ float wt[32][64];
  const int tid = threadIdx.x;
  const int n0 = blockIdx.x * 64;
  const int m0 = blockIdx.y * 64;
  const int kc = blockIdx.z;
  const int kbase = kc * 256;
  const int tm = tid & 15, tn = tid >> 4;
  float acc[4][4];
  #pragma unroll
  for (int i = 0; i < 4; ++i) { acc[i][0]=0.f; acc[i][1]=0.f; acc[i][2]=0.f; acc[i][3]=0.f; }
  for (int k0 = kbase; k0 < kbase + 256; k0 += 32) {
    __syncthreads();
    #pragma unroll
    for (int j = 0; j < 8; ++j) {
      int idx = tid + j * 256;
      int r = idx >> 5, kk = idx & 31;
      pt[r][kk] = P[(size_t)(m0 + r) * 1792 + k0 + kk];
    }
    #pragma unroll
    for (int j = 0; j < 8; ++j) {
      int idx = tid + j * 256;
      int kk = idx >> 6, nn = idx & 63;
      wt[kk][nn] = Wl1[(size_t)(k0 + kk) * 1792 + n0 + nn];
    }
    __syncthreads();
    #pragma unroll 4
    for (int k = 0; k < 32; ++k) {
      float4 bv = *(const float4*)&wt[k][tn << 2];
      #pragma unroll
      for (int i = 0; i < 4; ++i) {
        float av = pt[(tm << 2) + i][k];
        acc[i][0] = fmaf(av, bv.x, acc[i][0]);
        acc[i][1] = fmaf(av, bv.y, acc[i][1]);
        acc[i][2] = fmaf(av, bv.z, acc[i][2]);
        acc[i][3] = fmaf(av, bv.w, acc[i][3]);
      }
    }
  }
  float* pp = part + (size_t)kc * 458752;
  #pragma unroll
  for (int i = 0; i < 4; ++i) {
    int r = m0 + (tm << 2) + i;
    *(float4*)(pp + (size_t)r * 1792 + n0 + (tn << 2)) =
        make_float4(acc[i][0], acc[i][1], acc[i][2], acc[i][3]);
  }
}

__global__ void k_mlp1b(const float* __restrict__ part, const float* __restrict__ bl1,
                        float* __restrict__ hfin) {
  int idx = blockIdx.x * 256 + threadIdx.x;
  int n = idx % 1792;
  float s = bl1[n];
  #pragma unroll
  for (int kc = 0; kc < 7; ++kc) s += part[(size_t)kc * 458752 + idx];
  hfin[idx] = fmaxf(s, 0.f);
}

__global__ void k_mlp2(const float* __restrict__ hfin, const float* __restrict__ Wl2,
                       const float* __restrict__ bl2, float* __restrict__ out) {
  __shared__ float red[256];
  int g = blockIdx.x, t = threadIdx.x;
  float p = 0.f;
  for (int k = t; k < 1792; k += 256) p += hfin[(size_t)g * 1792 + k] * Wl2[k];
  red[t] = p;
  __syncthreads();
  for (int s = 128; s > 0; s >>= 1) {
    if (t < s) red[t] += red[t + s];
    __syncthreads();
  }
  if (t == 0) {
    float l = red[0] + bl2[0];
    out[g] = 1.f / (1.f + expf(-l));
    out[NG + g] = l;
  }
}

// ---------------- launch ----------------
extern "C" void kernel_launch(void* const* d_in, const int* in_sizes, int n_in,
                              void* d_out, int out_size, void* d_ws, size_t ws_size,
                              hipStream_t stream) {
  const float* x     = (const float*)d_in[0];
  const int*   edge  = (const int*)d_in[1];
  const int*   batch = (const int*)d_in[2];
  const float* W1    = (const float*)d_in[3];
  const float* b1    = (const float*)d_in[4];
  const float* gamma = (const float*)d_in[5];
  const float* beta  = (const float*)d_in[6];
  const float* W2    = (const float*)d_in[7];
  const float* b2    = (const float*)d_in[8];
  const float* Wl1   = (const float*)d_in[9];
  const float* bl1   = (const float*)d_in[10];
  const float* Wl2   = (const float*)d_in[11];
  const float* bl2   = (const float*)d_in[12];
  float* out = (float*)d_out;

  int* wsi = (int*)d_ws;
  int* row_ptr = wsi;             // 50048
  int* cursor  = wsi + 50048;     // 50048
  int* counts  = wsi + 100096;    // 50048
  int* csr_src = wsi + 150144;    // 800000
  int* bsum    = wsi + 950144;    // 256
  int* boff    = wsi + 950400;    // 256 (pad to 950912)
  float* wsf   = (float*)(wsi + 950912);
  float* A      = wsf;                 // [N,128] ping
  float* B      = wsf + 6400000;       // [N,128] pong
  float* psum   = wsf + 12800000;      // [782,128]
  float* psq    = wsf + 12900096;      // [782,128]
  float* ab     = wsf + 13000192;      // [2,128]
  float* pooled = wsf + 13000448;      // [256,1792]
  float* part = B;                     // MLP scratch aliases B (dead by then)
  float* hfin = B + 3211264;

  // CSR build (parallel scan) + pooled zero
  k_zero<<<1792, 256, 0, stream>>>(counts, pooled);
  k_hist<<<3125, 256, 0, stream>>>(edge, counts);
  k_part<<<196, 256, 0, stream>>>(counts, bsum);
  k_bscan<<<1, 256, 0, stream>>>(bsum, boff, row_ptr);
  k_rowptr<<<196, 256, 0, stream>>>(counts, boff, row_ptr, cursor);
  k_fill<<<3125, 256, 0, stream>>>(edge, cursor, csr_src);

  for (int i = 0; i < NLAY; ++i) {
    float* P = (i & 1) ? B : A;     // agg dst / h_i dst
    float* Q = (i & 1) ? A : B;     // z1 dst
    const float* hin = (i == 0) ? x : ((i & 1) ? A : B);
    k_agg<<<1563, 256, 0, stream>>>(hin, row_ptr, csr_src, P);
    k_gemm_bn<<<NBLK, 256, 0, stream>>>(P, W1 + i * 16384, b1 + i * 128, Q, psum, psq);
    k_bnstat2<<<1, 256, 0, stream>>>(psum, psq, gamma + i * 128, beta + i * 128, ab);
    k_gemm_pool<<<NBLK, 256, 0, stream>>>(Q, ab, W2 + i * 16384, b2 + i * 128, P,
                                          batch, pooled, i);
  }
  k_mlp1a<<<dim3(28, 4, 7), 256, 0, stream>>>(pooled, Wl1, part);
  k_mlp1b<<<1792, 256, 0, stream>>>(part, bl1, hfin);
  k_mlp2<<<256, 256, 0, stream>>>(hfin, Wl2, bl2, out);
}

// Round 4
// 1288.813 us; speedup vs baseline: 1.6029x; 1.6029x over previous
//
#include <hip/hip_runtime.h>
#include <cstdint>
#include <cstddef>

#define NN 50000
#define NE 800000
#define NG 256
#define NLAY 7
#define NBLK 782   // gemm blocks (64 rows each)

__device__ __forceinline__ float4 ld4(const float* p) { return *(const float4*)p; }
__device__ __forceinline__ void acc4(float4& a, const float4 b) {
  a.x += b.x; a.y += b.y; a.z += b.z; a.w += b.w;
}

// ---------------- init: zero counts + pooled ----------------
__global__ void k_zero(int* __restrict__ counts, float* __restrict__ pooled) {
  int i = blockIdx.x * 256 + threadIdx.x;  // grid 1792 -> 458752
  if (i < NN) counts[i] = 0;
  if (i < NG * 1792) pooled[i] = 0.f;
}

__global__ void k_hist(const int* __restrict__ edge, int* __restrict__ counts) {
  int e = blockIdx.x * 256 + threadIdx.x;
  if (e < NE) atomicAdd(&counts[edge[NE + e]], 1);
}

// ---------------- parallel CSR scan ----------------
__global__ void k_part(const int* __restrict__ counts, int* __restrict__ bsum) {
  __shared__ int sm[256];
  int b = blockIdx.x, t = threadIdx.x;
  int i = b * 256 + t;
  sm[t] = (i < NN) ? counts[i] : 0;
  __syncthreads();
  for (int s = 128; s > 0; s >>= 1) {
    if (t < s) sm[t] += sm[t + s];
    __syncthreads();
  }
  if (t == 0) bsum[b] = sm[0];
}

__global__ void k_bscan(const int* __restrict__ bsum, int* __restrict__ boff,
                        int* __restrict__ row_ptr) {
  __shared__ int sm[256];
  int t = threadIdx.x;
  int v = (t < 196) ? bsum[t] : 0;
  sm[t] = v;
  __syncthreads();
  int val = v;
  for (int off = 1; off < 256; off <<= 1) {
    int o = (t >= off) ? sm[t - off] : 0;
    __syncthreads();
    val += o;
    sm[t] = val;
    __syncthreads();
  }
  if (t < 196) boff[t] = val - v;  // exclusive
  if (t == 255) row_ptr[NN] = val; // total = NE
}

__global__ void k_rowptr(const int* __restrict__ counts, const int* __restrict__ boff,
                         int* __restrict__ row_ptr, int* __restrict__ cursor) {
  __shared__ int sm[256];
  int b = blockIdx.x, t = threadIdx.x;
  int i = b * 256 + t;
  int c = (i < NN) ? counts[i] : 0;
  sm[t] = c;
  __syncthreads();
  int val = c;
  for (int off = 1; off < 256; off <<= 1) {
    int o = (t >= off) ? sm[t - off] : 0;
    __syncthreads();
    val += o;
    sm[t] = val;
    __syncthreads();
  }
  int ex = val - c + boff[b];
  if (i < NN) { row_ptr[i] = ex; cursor[i] = ex; }
}

__global__ void k_fill(const int* __restrict__ edge, int* __restrict__ cursor,
                       int* __restrict__ csr_src) {
  int e = blockIdx.x * 256 + threadIdx.x;
  if (e < NE) {
    int pos = atomicAdd(&cursor[edge[NE + e]], 1);
    csr_src[pos] = edge[e];
  }
}

// ---------------- Aggregation: out[r] = h[r] + sum_{s in CSR[r]} h[s] ----------------
__global__ __launch_bounds__(256) void k_agg(
    const float* __restrict__ h, const int* __restrict__ row_ptr,
    const int* __restrict__ csr_src, float* __restrict__ out)
{
  int tid = threadIdx.x;
  int r = blockIdx.x * 32 + (tid >> 3);
  int sub = tid & 7;
  if (r >= NN) return;
  const float* hp = h + ((size_t)r << 7) + (sub << 4);
  float4 a0 = ld4(hp), a1 = ld4(hp + 4), a2 = ld4(hp + 8), a3 = ld4(hp + 12);
  float4 b0 = make_float4(0,0,0,0), b1 = b0, b2 = b0, b3 = b0;
  int e = row_ptr[r], e1 = row_ptr[r + 1];
  for (; e + 1 < e1; e += 2) {
    const float* p0 = h + ((size_t)csr_src[e] << 7) + (sub << 4);
    const float* p1 = h + ((size_t)csr_src[e + 1] << 7) + (sub << 4);
    float4 v0 = ld4(p0), v1 = ld4(p0 + 4), v2 = ld4(p0 + 8), v3 = ld4(p0 + 12);
    float4 w0 = ld4(p1), w1 = ld4(p1 + 4), w2 = ld4(p1 + 8), w3 = ld4(p1 + 12);
    acc4(a0, v0); acc4(a1, v1); acc4(a2, v2); acc4(a3, v3);
    acc4(b0, w0); acc4(b1, w1); acc4(b2, w2); acc4(b3, w3);
  }
  if (e < e1) {
    const float* p0 = h + ((size_t)csr_src[e] << 7) + (sub << 4);
    acc4(a0, ld4(p0)); acc4(a1, ld4(p0 + 4)); acc4(a2, ld4(p0 + 8)); acc4(a3, ld4(p0 + 12));
  }
  acc4(a0, b0); acc4(a1, b1); acc4(a2, b2); acc4(a3, b3);
  float* op = out + ((size_t)r << 7) + (sub << 4);
  *(float4*)op = a0; *(float4*)(op + 4) = a1;
  *(float4*)(op + 8) = a2; *(float4*)(op + 12) = a3;
}

// ---------------- GEMM1: z1 = agg @ W1 + b1, fused per-block BN partial stats ----------------
__global__ __launch_bounds__(256) void k_gemm_bn(
    const float* __restrict__ in, const float* __restrict__ W,
    const float* __restrict__ bias, float* __restrict__ out,
    float* __restrict__ psum, float* __restrict__ psq)
{
  __shared__ float zs[64][132];
  __shared__ float wsm[32][128];
  const int tid = threadIdx.x;
  const int m0 = blockIdx.x * 64;
  const int lane = tid & 31;
  const int rgrp = tid >> 5;
  for (int pass = 0; pass < 8; ++pass) {
    const int lr = pass * 8 + rgrp;
    const int r = m0 + lr;
    float4 v = make_float4(0.f, 0.f, 0.f, 0.f);
    if (r < NN) v = ld4(in + ((size_t)r << 7) + (lane << 2));
    *(float4*)&zs[lr][lane << 2] = v;
  }

  float acc[8][4];
  #pragma unroll
  for (int i = 0; i < 8; ++i) { acc[i][0]=0.f; acc[i][1]=0.f; acc[i][2]=0.f; acc[i][3]=0.f; }
  const int tm = tid >> 5, tn = tid & 31;
  for (int k0 = 0; k0 < 128; k0 += 32) {
    __syncthreads();
    #pragma unroll
    for (int j = 0; j < 16; ++j) {
      int idx = tid + j * 256;
      wsm[idx >> 7][idx & 127] = W[((size_t)(k0 + (idx >> 7)) << 7) + (idx & 127)];
    }
    __syncthreads();
    #pragma unroll 4
    for (int k = 0; k < 32; ++k) {
      float4 bv = *(const float4*)&wsm[k][tn << 2];
      #pragma unroll
      for (int i = 0; i < 8; ++i) {
        float av = zs[(tm << 3) + i][k0 + k];
        acc[i][0] = fmaf(av, bv.x, acc[i][0]);
        acc[i][1] = fmaf(av, bv.y, acc[i][1]);
        acc[i][2] = fmaf(av, bv.z, acc[i][2]);
        acc[i][3] = fmaf(av, bv.w, acc[i][3]);
      }
    }
  }
  float4 bb = ld4(bias + (tn << 2));
  float s0=0,s1=0,s2=0,s3=0,q0=0,q1=0,q2=0,q3=0;
  #pragma unroll
  for (int i = 0; i < 8; ++i) {
    int r = m0 + (tm << 3) + i;
    if (r < NN) {
      float4 o = make_float4(acc[i][0] + bb.x, acc[i][1] + bb.y,
                             acc[i][2] + bb.z, acc[i][3] + bb.w);
      *(float4*)(out + ((size_t)r << 7) + (tn << 2)) = o;
      s0 += o.x; q0 += o.x*o.x;
      s1 += o.y; q1 += o.y*o.y;
      s2 += o.z; q2 += o.z*o.z;
      s3 += o.w; q3 += o.w*o.w;
    }
  }
  // reduce over tm (8 groups) per column
  __syncthreads();
  float* reds = (float*)zs;          // 1024 floats
  float* redq = ((float*)zs) + 1024; // 1024 floats
  int cb = tn << 2;
  reds[(cb+0)*8+tm]=s0; reds[(cb+1)*8+tm]=s1; reds[(cb+2)*8+tm]=s2; reds[(cb+3)*8+tm]=s3;
  redq[(cb+0)*8+tm]=q0; redq[(cb+1)*8+tm]=q1; redq[(cb+2)*8+tm]=q2; redq[(cb+3)*8+tm]=q3;
  __syncthreads();
  if (tid < 128) {
    float s = 0.f, q = 0.f;
    #pragma unroll
    for (int k = 0; k < 8; ++k) { s += reds[tid*8+k]; q += redq[tid*8+k]; }
    psum[blockIdx.x * 128 + tid] = s;
    psq[blockIdx.x * 128 + tid] = q;
  }
}

// ---------------- BN finalize (parallel): one block per column ----------------
__global__ __launch_bounds__(256) void k_bnfin(
    const float* __restrict__ psum, const float* __restrict__ psq,
    const float* __restrict__ gamma, const float* __restrict__ beta,
    float* __restrict__ ab) {
  __shared__ float ss[256], sq[256];
  int col = blockIdx.x;   // 128
  int t = threadIdx.x;    // 256
  float s = 0.f, q = 0.f;
  for (int b = t; b < NBLK; b += 256) {
    s += psum[b * 128 + col];
    q += psq[b * 128 + col];
  }
  ss[t] = s; sq[t] = q;
  __syncthreads();
  for (int st = 128; st > 0; st >>= 1) {
    if (t < st) { ss[t] += ss[t + st]; sq[t] += sq[t + st]; }
    __syncthreads();
  }
  if (t == 0) {
    float mean = ss[0] * (1.f / NN);
    float var = sq[0] * (1.f / NN) - mean * mean;
    float rstd = rsqrtf(var + 1e-5f);
    float a = gamma[col] * rstd;
    ab[col] = a;
    ab[128 + col] = beta[col] - mean * a;
  }
}

// ---------------- GEMM2: h = relu(affrelu(z1) @ W2 + b2), fused pooling ----------------
__global__ __launch_bounds__(256) void k_gemm_pool(
    const float* __restrict__ in, const float* __restrict__ ab,
    const float* __restrict__ W, const float* __restrict__ bias,
    float* __restrict__ out, const int* __restrict__ batch,
    float* __restrict__ pooled, int layer)
{
  __shared__ float zs[64][132];
  __shared__ float wsm[32][128];
  const int tid = threadIdx.x;
  const int m0 = blockIdx.x * 64;
  const int lane = tid & 31;
  const int rgrp = tid >> 5;
  float4 aa = ld4(ab + (lane << 2));
  float4 ob = ld4(ab + 128 + (lane << 2));
  for (int pass = 0; pass < 8; ++pass) {
    const int lr = pass * 8 + rgrp;
    const int r = m0 + lr;
    float4 v = make_float4(0.f, 0.f, 0.f, 0.f);
    if (r < NN) v = ld4(in + ((size_t)r << 7) + (lane << 2));
    float4 y;
    y.x = fmaxf(fmaf(aa.x, v.x, ob.x), 0.f);
    y.y = fmaxf(fmaf(aa.y, v.y, ob.y), 0.f);
    y.z = fmaxf(fmaf(aa.z, v.z, ob.z), 0.f);
    y.w = fmaxf(fmaf(aa.w, v.w, ob.w), 0.f);
    *(float4*)&zs[lr][lane << 2] = y;
  }

  float acc[8][4];
  #pragma unroll
  for (int i = 0; i < 8; ++i) { acc[i][0]=0.f; acc[i][1]=0.f; acc[i][2]=0.f; acc[i][3]=0.f; }
  const int tm = tid >> 5, tn = tid & 31;
  for (int k0 = 0; k0 < 128; k0 += 32) {
    __syncthreads();
    #pragma unroll
    for (int j = 0; j < 16; ++j) {
      int idx = tid + j * 256;
      wsm[idx >> 7][idx & 127] = W[((size_t)(k0 + (idx >> 7)) << 7) + (idx & 127)];
    }
    __syncthreads();
    #pragma unroll 4
    for (int k = 0; k < 32; ++k) {
      float4 bv = *(const float4*)&wsm[k][tn << 2];
      #pragma unroll
      for (int i = 0; i < 8; ++i) {
        float av = zs[(tm << 3) + i][k0 + k];
        acc[i][0] = fmaf(av, bv.x, acc[i][0]);
        acc[i][1] = fmaf(av, bv.y, acc[i][1]);
        acc[i][2] = fmaf(av, bv.z, acc[i][2]);
        acc[i][3] = fmaf(av, bv.w, acc[i][3]);
      }
    }
  }
  float4 bb = ld4(bias + (tn << 2));
  // apply relu into acc, store
  int bgi[8];
  #pragma unroll
  for (int i = 0; i < 8; ++i) {
    int r = m0 + (tm << 3) + i;
    bgi[i] = (r < NN) ? batch[r] : -1;
    if (r < NN) {
      acc[i][0] = fmaxf(acc[i][0] + bb.x, 0.f);
      acc[i][1] = fmaxf(acc[i][1] + bb.y, 0.f);
      acc[i][2] = fmaxf(acc[i][2] + bb.z, 0.f);
      acc[i][3] = fmaxf(acc[i][3] + bb.w, 0.f);
      *(float4*)(out + ((size_t)r << 7) + (tn << 2)) =
          make_float4(acc[i][0], acc[i][1], acc[i][2], acc[i][3]);
    }
  }
  // fused pooling: rows m0..m0+63 span batch[m0]..batch[min(m0+63,NN-1)] graphs
  int gstart = batch[m0];
  int gend = batch[(m0 + 63 < NN) ? (m0 + 63) : (NN - 1)];
  float* reds = (float*)zs;
  float* redm = ((float*)zs) + 1024;
  int cb = tn << 2;
  for (int g = gstart; g <= gend; ++g) {
    float s[4] = {0.f,0.f,0.f,0.f}, mx[4] = {0.f,0.f,0.f,0.f};
    #pragma unroll
    for (int i = 0; i < 8; ++i) {
      if (bgi[i] == g) {
        s[0] += acc[i][0]; mx[0] = fmaxf(mx[0], acc[i][0]);
        s[1] += acc[i][1]; mx[1] = fmaxf(mx[1], acc[i][1]);
        s[2] += acc[i][2]; mx[2] = fmaxf(mx[2], acc[i][2]);
        s[3] += acc[i][3]; mx[3] = fmaxf(mx[3], acc[i][3]);
      }
    }
    __syncthreads();
    #pragma unroll
    for (int j = 0; j < 4; ++j) {
      reds[(cb+j)*8+tm] = s[j];
      redm[(cb+j)*8+tm] = mx[j];
    }
    __syncthreads();
    if (tid < 128) {
      float ss = 0.f, sm = 0.f;
      #pragma unroll
      for (int k = 0; k < 8; ++k) { ss += reds[tid*8+k]; sm = fmaxf(sm, redm[tid*8+k]); }
      if (ss != 0.f) atomicAdd(&pooled[g * 1792 + layer * 128 + tid], ss);
      if (sm != 0.f)
        atomicMax((int*)&pooled[g * 1792 + 896 + layer * 128 + tid], __float_as_int(sm));
    }
  }
}

// ---------------- Final MLP: split-K partials ----------------
__global__ __launch_bounds__(256) void k_mlp1a(
    const float* __restrict__ P, const float* __restrict__ Wl1,
    float* __restrict__ part)
{
  __shared__ float pt[64][33];
  __shared__ float wt[32][64];
  const int tid = threadIdx.x;
  const int n0 = blockIdx.x * 64;
  const int m0 = blockIdx.y * 64;
  const int kc = blockIdx.z;
  const int kbase = kc * 256;
  const int tm = tid & 15, tn = tid >> 4;
  float acc[4][4];
  #pragma unroll
  for (int i = 0; i < 4; ++i) { acc[i][0]=0.f; acc[i][1]=0.f; acc[i][2]=0.f; acc[i][3]=0.f; }
  for (int k0 = kbase; k0 < kbase + 256; k0 += 32) {
    __syncthreads();
    #pragma unroll
    for (int j = 0; j < 8; ++j) {
      int idx = tid + j * 256;
      int r = idx >> 5, kk = idx & 31;
      pt[r][kk] = P[(size_t)(m0 + r) * 1792 + k0 + kk];
    }
    #pragma unroll
    for (int j = 0; j < 8; ++j) {
      int idx = tid + j * 256;
      int kk = idx >> 6, nn = idx & 63;
      wt[kk][nn] = Wl1[(size_t)(k0 + kk) * 1792 + n0 + nn];
    }
    __syncthreads();
    #pragma unroll 4
    for (int k = 0; k < 32; ++k) {
      float4 bv = *(const float4*)&wt[k][tn << 2];
      #pragma unroll
      for (int i = 0; i < 4; ++i) {
        float av = pt[(tm << 2) + i][k];
        acc[i][0] = fmaf(av, bv.x, acc[i][0]);
        acc[i][1] = fmaf(av, bv.y, acc[i][1]);
        acc[i][2] = fmaf(av, bv.z, acc[i][2]);
        acc[i][3] = fmaf(av, bv.w, acc[i][3]);
      }
    }
  }
  float* pp = part + (size_t)kc * 458752;
  #pragma unroll
  for (int i = 0; i < 4; ++i) {
    int r = m0 + (tm << 2) + i;
    *(float4*)(pp + (size_t)r * 1792 + n0 + (tn << 2)) =
        make_float4(acc[i][0], acc[i][1], acc[i][2], acc[i][3]);
  }
}

__global__ void k_mlp1b(const float* __restrict__ part, const float* __restrict__ bl1,
                        float* __restrict__ hfin) {
  int idx = blockIdx.x * 256 + threadIdx.x;
  int n = idx % 1792;
  float s = bl1[n];
  #pragma unroll
  for (int kc = 0; kc < 7; ++kc) s += part[(size_t)kc * 458752 + idx];
  hfin[idx] = fmaxf(s, 0.f);
}

__global__ void k_mlp2(const float* __restrict__ hfin, const float* __restrict__ Wl2,
                       const float* __restrict__ bl2, float* __restrict__ out) {
  __shared__ float red[256];
  int g = blockIdx.x, t = threadIdx.x;
  float p = 0.f;
  for (int k = t; k < 1792; k += 256) p += hfin[(size_t)g * 1792 + k] * Wl2[k];
  red[t] = p;
  __syncthreads();
  for (int s = 128; s > 0; s >>= 1) {
    if (t < s) red[t] += red[t + s];
    __syncthreads();
  }
  if (t == 0) {
    float l = red[0] + bl2[0];
    out[g] = 1.f / (1.f + expf(-l));
    out[NG + g] = l;
  }
}

// ---------------- launch ----------------
extern "C" void kernel_launch(void* const* d_in, const int* in_sizes, int n_in,
                              void* d_out, int out_size, void* d_ws, size_t ws_size,
                              hipStream_t stream) {
  const float* x     = (const float*)d_in[0];
  const int*   edge  = (const int*)d_in[1];
  const int*   batch = (const int*)d_in[2];
  const float* W1    = (const float*)d_in[3];
  const float* b1    = (const float*)d_in[4];
  const float* gamma = (const float*)d_in[5];
  const float* beta  = (const float*)d_in[6];
  const float* W2    = (const float*)d_in[7];
  const float* b2    = (const float*)d_in[8];
  const float* Wl1   = (const float*)d_in[9];
  const float* bl1   = (const float*)d_in[10];
  const float* Wl2   = (const float*)d_in[11];
  const float* bl2   = (const float*)d_in[12];
  float* out = (float*)d_out;

  int* wsi = (int*)d_ws;
  int* row_ptr = wsi;             // 50048
  int* cursor  = wsi + 50048;     // 50048
  int* counts  = wsi + 100096;    // 50048
  int* csr_src = wsi + 150144;    // 800000
  int* bsum    = wsi + 950144;    // 256
  int* boff    = wsi + 950400;    // 256 (pad to 950912)
  float* wsf   = (float*)(wsi + 950912);
  float* A      = wsf;                 // [N,128] ping
  float* B      = wsf + 6400000;       // [N,128] pong
  float* psum   = wsf + 12800000;      // [782,128]
  float* psq    = wsf + 12900096;      // [782,128]
  float* ab     = wsf + 13000192;      // [2,128]
  float* pooled = wsf + 13000448;      // [256,1792]
  float* part = B;                     // MLP scratch aliases B (dead by then)
  float* hfin = B + 3211264;

  // CSR build (parallel scan) + pooled zero
  k_zero<<<1792, 256, 0, stream>>>(counts, pooled);
  k_hist<<<3125, 256, 0, stream>>>(edge, counts);
  k_part<<<196, 256, 0, stream>>>(counts, bsum);
  k_bscan<<<1, 256, 0, stream>>>(bsum, boff, row_ptr);
  k_rowptr<<<196, 256, 0, stream>>>(counts, boff, row_ptr, cursor);
  k_fill<<<3125, 256, 0, stream>>>(edge, cursor, csr_src);

  for (int i = 0; i < NLAY; ++i) {
    float* P = (i & 1) ? B : A;     // agg dst / h_i dst
    float* Q = (i & 1) ? A : B;     // z1 dst
    const float* hin = (i == 0) ? x : ((i & 1) ? A : B);
    k_agg<<<1563, 256, 0, stream>>>(hin, row_ptr, csr_src, P);
    k_gemm_bn<<<NBLK, 256, 0, stream>>>(P, W1 + i * 16384, b1 + i * 128, Q, psum, psq);
    k_bnfin<<<128, 256, 0, stream>>>(psum, psq, gamma + i * 128, beta + i * 128, ab);
    k_gemm_pool<<<NBLK, 256, 0, stream>>>(Q, ab, W2 + i * 16384, b2 + i * 128, P,
                                          batch, pooled, i);
  }
  k_mlp1a<<<dim3(28, 4, 7), 256, 0, stream>>>(pooled, Wl1, part);
  k_mlp1b<<<1792, 256, 0, stream>>>(part, bl1, hfin);
  k_mlp2<<<256, 256, 0, stream>>>(hfin, Wl2, bl2, out);
}